// Round 17
// baseline (145.945 us; speedup 1.0000x reference)
//
#include <hip/hip_runtime.h>

typedef _Float16 half_t;
typedef _Float16 h2 __attribute__((ext_vector_type(2)));
typedef _Float16 h4 __attribute__((ext_vector_type(4)));
typedef _Float16 f16x8 __attribute__((ext_vector_type(8)));
typedef float f32x4 __attribute__((ext_vector_type(4)));

// ws layout (floats): wdt [0,320) ; w2B halves at +320 (1536 h) ; w3B halves at +1088 (5120 h)
__global__ __launch_bounds__(256) void prep_kernel(
    const float* __restrict__ w2g, const float* __restrict__ w3g,
    const float* __restrict__ wdg, float* __restrict__ wsW)
{
    const int tid = threadIdx.x;
    half_t* w2B = (half_t*)(wsW + 320);
    half_t* w3B = (half_t*)(wsW + 1088);
    for (int i = tid; i < 320; i += 256) {             // wdt[c2*10+j] = wd[j][c2]
        int j = i >> 5, c2 = i & 31;
        wsW[c2 * 10 + j] = wdg[i];
    }
    // stage-2 B-fragments (mfma 16x16x32): lane holds B[k=c*32+(lane>>4)*8+j][n=lane&15]
    // k = (g*9+tap)*4 + l ; value = w2[oc=n][ic=g*4+l][tap] ; k>=72 -> 0
    for (int i = tid; i < 1536; i += 256) {
        int c    = i >> 9;
        int r    = i & 511;
        int lane = r >> 3;
        int j    = r & 7;
        int k    = c * 32 + ((lane >> 4) << 3) + j;
        half_t val = (half_t)0.f;
        if (k < 72) {
            int t = k >> 2, l = k & 3;
            int g = (t >= 9) ? 1 : 0;
            int tap = t - 9 * g;
            int oc  = lane & 15;
            val = (half_t)w2g[(oc * 8 + g * 4 + l) * 9 + tap];
        }
        w2B[i] = val;
    }
    // stage-3 B-fragments: GEMM M=16(img*4+win), N=16/tile (oc=tile*16+n), K=144 (k=tap*16+ic)
    for (int i = tid; i < 5120; i += 256) {
        int j    = i & 7;
        int lane = (i >> 3) & 63;
        int tc   = i >> 9;            // 0..9
        int tile = tc / 5;
        int c    = tc - tile * 5;
        int k    = c * 32 + ((lane >> 4) << 3) + j;
        int n    = lane & 15;
        half_t val = (half_t)0.f;
        if (k < 144) {
            int ic = k & 15, tap = k >> 4;
            val = (half_t)w3g[((tile * 16 + n) * 16 + ic) * 9 + tap];
        }
        w3B[i] = val;
    }
}

// 4 images per block (grid 2048 = 256 CU x 8 blocks, fully co-resident), 256 threads.
// fp16 image in LDS (~15.9 KB total) + launch_bounds(256,8) -> 8 blocks/CU, ONE round.
__global__ __launch_bounds__(256, 8) void cnn_kernel(
    const float* __restrict__ seq,
    const float* __restrict__ w1g, const float* __restrict__ b1g,
    const float* __restrict__ b2g, const float* __restrict__ b3g,
    const float* __restrict__ bdg, const float* __restrict__ wsW,
    float* __restrict__ out)
{
    __shared__ __align__(16) half_t s_img2[4][28][28];      // parity: [0..13]=even, [14..27]=odd
    __shared__ __align__(16) half_t s_p1n[4][2][10][11][4]; // [img][g][y][slot][l]; ic=g*4+l
    __shared__ __align__(16) half_t s_p2n[4][16][16];       // [img][pixel(y*4+x)][16 ic]
    __shared__ float s_p3[4][32];

    const int tid   = threadIdx.x;
    const int mbase = blockIdx.x * 4;
    const float*  wdt = wsW;
    const half_t* w2B = (const half_t*)(wsW + 320);
    const half_t* w3B = (const half_t*)(wsW + 1088);

    // ---- stage images (parity de-interleave, fp32 -> fp16)
    if (tid < 196) {
        #pragma unroll
        for (int img = 0; img < 4; img++) {
            const int m = mbase + img;
            const int b = m & 255, nn = m >> 8;
            const int t = nn >> 2, dd = nn & 3;
            const float4* s4 = (const float4*)(seq + (((size_t)b * 8 + t) * 4 + dd) * 784);
            float4 v = s4[tid];
            int flat = tid * 4;
            int r  = flat / 28;
            int cb = flat - r * 28;       // multiple of 4
            int e  = cb >> 1;             // even
            h2 ev = { (half_t)v.x, (half_t)v.z };
            h2 od = { (half_t)v.y, (half_t)v.w };
            *(h2*)&s_img2[img][r][e]      = ev;
            *(h2*)&s_img2[img][r][14 + e] = od;
        }
    }
    __syncthreads();

    // ---- stage 1: conv1(1->8)+relu+pool2 at the 100 needed positions/image (400 items).
    for (int idx = tid; idx < 400; idx += 256) {
        const int img = idx / 100;
        const int rem = idx - img * 100;
        const int y   = rem / 10;
        const int x   = rem - y * 10;
        const int r0  = 2 * y;
        float p[4][4];
        #pragma unroll
        for (int i = 0; i < 4; i++) {
            const half_t* rp = &s_img2[img][r0 + i][0];
            h2 e2 = *(const h2*)&rp[x];        // cols 2x, 2x+2
            h2 o2 = *(const h2*)&rp[14 + x];   // cols 2x+1, 2x+3
            p[i][0] = (float)e2[0];
            p[i][1] = (float)o2[0];
            p[i][2] = (float)e2[1];
            p[i][3] = (float)o2[1];
        }
        float res[8];
        #pragma unroll
        for (int c = 0; c < 8; c++) {
            float w[9];
            #pragma unroll
            for (int k = 0; k < 9; k++) w[k] = w1g[c * 9 + k];   // uniform -> s_load
            const float bias = b1g[c];
            float acc = 0.f;
            #pragma unroll
            for (int rr = 0; rr < 2; rr++)
                #pragma unroll
                for (int cc = 0; cc < 2; cc++) {
                    float v = bias;
                    #pragma unroll
                    for (int i = 0; i < 3; i++)
                        #pragma unroll
                        for (int j = 0; j < 3; j++)
                            v += p[rr + i][cc + j] * w[i * 3 + j];
                    acc += fmaxf(v, 0.f);
                }
            res[c] = 0.25f * acc;
        }
        const int slot = (x >> 1) + 5 * (x & 1);
        h4 lo = { (half_t)res[0], (half_t)res[1], (half_t)res[2], (half_t)res[3] };
        h4 hi = { (half_t)res[4], (half_t)res[5], (half_t)res[6], (half_t)res[7] };
        *(h4*)&s_p1n[img][0][y][slot][0] = lo;
        *(h4*)&s_p1n[img][1][y][slot][0] = hi;
    }
    __syncthreads();

    const int img2 = tid >> 6;          // wave = image (stage 2)
    const int t6   = tid & 63;

    // ---- stage 2 (MFMA): conv2 at 8x8 conv grid + relu + pool -> s_p2n.
    {
        const int q  = t6 >> 4;
        const int oc = t6 & 15;
        int tg[6], ti[6], tj[6];
        bool tv[6];
        #pragma unroll
        for (int c = 0; c < 3; c++)
            #pragma unroll
            for (int s = 0; s < 2; s++) {
                int e = c * 2 + s;
                int t = c * 8 + q * 2 + s;
                bool v = (t < 18);
                int tt = v ? t : 0;
                int g = (tt >= 9) ? 1 : 0;
                int tap = tt - 9 * g;
                tg[e] = g; ti[e] = tap / 3; tj[e] = tap - 3 * (tap / 3); tv[e] = v;
            }
        f16x8 B[3];
        #pragma unroll
        for (int c = 0; c < 3; c++)
            B[c] = *(const f16x8*)&w2B[(c * 64 + t6) * 8];

        const float bias = b2g[oc];
        f32x4 acc[4];
        #pragma unroll
        for (int T = 0; T < 4; T++) {
            acc[T][0] = bias; acc[T][1] = bias; acc[T][2] = bias; acc[T][3] = bias;
        }
        const int mm = t6 & 15;
        #pragma unroll
        for (int T = 0; T < 4; T++) {
            const int cy = 2 * T + (mm >> 3);
            const int cx = mm & 7;
            #pragma unroll
            for (int c = 0; c < 3; c++) {
                h4 a0, a1;
                #pragma unroll
                for (int z = 0; z < 4; z++) { a0[z] = (half_t)0.f; a1[z] = (half_t)0.f; }
                const int e0 = c * 2, e1 = c * 2 + 1;
                if (tv[e0]) {
                    int col = cx + tj[e0];
                    int slot = (col >> 1) + 5 * (col & 1);
                    a0 = *(const h4*)&s_p1n[img2][tg[e0]][cy + ti[e0]][slot][0];
                }
                if (tv[e1]) {
                    int col = cx + tj[e1];
                    int slot = (col >> 1) + 5 * (col & 1);
                    a1 = *(const h4*)&s_p1n[img2][tg[e1]][cy + ti[e1]][slot][0];
                }
                f16x8 A = __builtin_shufflevector(a0, a1, 0, 1, 2, 3, 4, 5, 6, 7);
                acc[T] = __builtin_amdgcn_mfma_f32_16x16x32_f16(A, B[c], acc[T], 0, 0, 0);
            }
        }
        #pragma unroll
        for (int T = 0; T < 4; T++) {
            float p0 = fmaxf(acc[T][0], 0.f) + fmaxf(acc[T][1], 0.f);
            float p1 = fmaxf(acc[T][2], 0.f) + fmaxf(acc[T][3], 0.f);
            p0 += __shfl_xor(p0, 32, 64);          // pool over cy
            p1 += __shfl_xor(p1, 32, 64);
            if (q < 2) {
                s_p2n[img2][T * 4 + q * 2    ][oc] = (half_t)(0.25f * p0);
                s_p2n[img2][T * 4 + q * 2 + 1][oc] = (half_t)(0.25f * p1);
            }
        }
    }
    __syncthreads();

    // ---- stage 3 (MFMA, block-level): waves 0/1; tile = wave (oc base tile*16).
    if ((tid >> 6) < 2) {
        const int tile = tid >> 6;
        const int lane = tid & 63;
        const int n    = lane & 15;
        const int quad = lane >> 4;
        const int oc   = tile * 16 + n;
        const int am   = lane & 15;            // A row index held by this lane
        const int aimg = am >> 2;
        const int awin = am & 3;
        const int au   = awin >> 1, av = awin & 1;
        const int icb  = (quad & 1) * 8;

        float bias = b3g[oc];
        f32x4 acc;
        acc[0] = bias; acc[1] = bias; acc[2] = bias; acc[3] = bias;
        #pragma unroll
        for (int c = 0; c < 5; c++) {
            const int tap = c * 2 + (quad >> 1);
            f16x8 A;
            if (tap < 9) {
                const int i = tap / 3, j = tap - 3 * i;
                A = *(const f16x8*)&s_p2n[aimg][(au + i) * 4 + (av + j)][icb];
            } else {
                #pragma unroll
                for (int z = 0; z < 8; z++) A[z] = (half_t)0.f;
            }
            f16x8 B = *(const f16x8*)&w3B[((tile * 5 + c) * 64 + lane) * 8];
            acc = __builtin_amdgcn_mfma_f32_16x16x32_f16(A, B, acc, 0, 0, 0);
        }
        float s = fmaxf(acc[0], 0.f) + fmaxf(acc[1], 0.f) +
                  fmaxf(acc[2], 0.f) + fmaxf(acc[3], 0.f);
        s_p3[quad][oc] = 0.25f * s;
    }
    __syncthreads();

    // ---- dense + shfl softmax + guards (per wave = per image)
    {
        float logit = -1e30f;
        if (t6 < 10) {
            float acc = bdg[t6];
            #pragma unroll
            for (int c2 = 0; c2 < 32; c2++) acc += s_p3[img2][c2] * wdt[c2 * 10 + t6];
            logit = acc;
        }
        float mx = logit;
        #pragma unroll
        for (int s = 1; s < 16; s <<= 1) mx = fmaxf(mx, __shfl_xor(mx, s, 16));
        float e = (t6 < 10) ? __expf(logit - mx) : 0.f;
        float ssum = e;
        #pragma unroll
        for (int s = 1; s < 16; s <<= 1) ssum += __shfl_xor(ssum, s, 16);
        float p = e / ssum;                        // lanes 10..15 -> p = 0
        const int m = mbase + img2;
        if (t6 < 10) out[(size_t)m * 10 + t6] = p; // all_cnn_preds (N,B,10)

        // guards: [p8, p4+p6, p0+p2, p7+p9, p5, p1+p3]; 0xF slot reads lane 15 (p=0)
        const int sh = (t6 < 6 ? t6 : 0) * 4;
        const int ia = (0x157048 >> sh) & 0xF;
        const int ib = (0x3F926F >> sh) & 0xF;
        float pa = __shfl(p, ia, 16);
        float pb = __shfl(p, ib, 16);
        if (t6 < 6)
            out[81920 + (size_t)m * 6 + t6] = pa + pb;    // all_guard_preds (N,B,6)
    }
}

// 11 blocks x 256 threads. lane = bb*10 + j inside a wave (6 batches/wave).
__global__ __launch_bounds__(256) void sfa_kernel(
    const float* __restrict__ trans,
    const float* __restrict__ out_guards,   // = out (guards at +81920)
    float* __restrict__ out)
{
    __shared__ float M[600];           // [r][i][j]
    const int tid  = threadIdx.x;
    const int lane = tid & 63;
    const int wv   = tid >> 6;

    if (tid < 54) {
        int r = tid / 9, i = tid - r * 9;
        const float* row = trans + (size_t)(r * 9 + i) * 10;
        float x[10], mx = -1e30f;
        #pragma unroll
        for (int j = 0; j < 10; j++) { x[j] = 10.f * row[j]; mx = fmaxf(mx, x[j]); }
        float s = 0.f;
        #pragma unroll
        for (int j = 0; j < 10; j++) { x[j] = __expf(x[j] - mx); s += x[j]; }
        float inv = 1.f / s;
        #pragma unroll
        for (int j = 0; j < 10; j++) M[(r * 9 + i) * 10 + j] = x[j] * inv;
    }
    __syncthreads();

    const int bb    = lane / 10;
    const int j     = lane - bb * 10;
    const int base  = bb * 10;
    const bool ok   = (bb < 6);
    int batch = blockIdx.x * 24 + wv * 6 + bb;
    const bool live = ok && (batch < 256);
    if (!live) batch = 0;

    float Mreg[54];
    #pragma unroll
    for (int k = 0; k < 54; k++) Mreg[k] = M[k * 10 + j];

    float stj = (j == 0) ? 1.f : 0.f;
    const float* gbase = out_guards + 81920;

    for (int nn = 0; nn < 32; nn++) {
        const float* gp = gbase + ((size_t)nn * 256 + batch) * 6;
        float2 ga = *(const float2*)(gp);
        float2 gb = *(const float2*)(gp + 2);
        float2 gc = *(const float2*)(gp + 4);
        float g[6] = {ga.x, ga.y, gb.x, gb.y, gc.x, gc.y};

        float st[10];
        #pragma unroll
        for (int i = 0; i < 10; i++) st[i] = __shfl(stj, base + i, 64);

        float gsum = g[0] + g[1] + g[2] + g[3] + g[4] + g[5];
        float ns = (j == 9) ? gsum * st[9] : 0.f;   // accepting row
        #pragma unroll
        for (int r = 0; r < 6; r++) {
            float h = 0.f;
            #pragma unroll
            for (int i = 0; i < 9; i++) h += st[i] * Mreg[r * 9 + i];
            ns += g[r] * h;
        }
        stj = ns;
    }
    if (live) out[131072 + (size_t)batch * 10 + j] = stj;   // state_final (B,10)
}

extern "C" void kernel_launch(void* const* d_in, const int* in_sizes, int n_in,
                              void* d_out, int out_size, void* d_ws, size_t ws_size,
                              hipStream_t stream) {
    const float* seq = (const float*)d_in[0];
    const float* w1  = (const float*)d_in[1];
    const float* b1  = (const float*)d_in[2];
    const float* w2  = (const float*)d_in[3];
    const float* b2  = (const float*)d_in[4];
    const float* w3  = (const float*)d_in[5];
    const float* b3  = (const float*)d_in[6];
    const float* wd  = (const float*)d_in[7];
    const float* bd  = (const float*)d_in[8];
    const float* tr  = (const float*)d_in[9];
    float* out = (float*)d_out;
    float* wsW = (float*)d_ws;             // wdt + w2B + w3B fragments

    prep_kernel<<<1, 256, 0, stream>>>(w2, w3, wd, wsW);
    cnn_kernel<<<2048, 256, 0, stream>>>(seq, w1, b1, b2, b3, bd, wsW, out);
    sfa_kernel<<<11, 256, 0, stream>>>(tr, out, out);
}

// Round 18
// 137.893 us; speedup vs baseline: 1.0584x; 1.0584x over previous
//
#include <hip/hip_runtime.h>

typedef _Float16 half_t;
typedef _Float16 h2 __attribute__((ext_vector_type(2)));
typedef _Float16 h4 __attribute__((ext_vector_type(4)));
typedef _Float16 f16x8 __attribute__((ext_vector_type(8)));
typedef float f32x4 __attribute__((ext_vector_type(4)));

// ws layout (floats): wdt [0,320) ; w2B halves at +320 (1536 h) ; w3B halves at +1088 (5120 h)
__global__ __launch_bounds__(256) void prep_kernel(
    const float* __restrict__ w2g, const float* __restrict__ w3g,
    const float* __restrict__ wdg, float* __restrict__ wsW)
{
    const int tid = threadIdx.x;
    half_t* w2B = (half_t*)(wsW + 320);
    half_t* w3B = (half_t*)(wsW + 1088);
    for (int i = tid; i < 320; i += 256) {             // wdt[c2*10+j] = wd[j][c2]
        int j = i >> 5, c2 = i & 31;
        wsW[c2 * 10 + j] = wdg[i];
    }
    // stage-2 B-fragments (mfma 16x16x32): lane holds B[k=c*32+(lane>>4)*8+j][n=lane&15]
    // k = (g*9+tap)*4 + l ; value = w2[oc=n][ic=g*4+l][tap] ; k>=72 -> 0
    for (int i = tid; i < 1536; i += 256) {
        int c    = i >> 9;
        int r    = i & 511;
        int lane = r >> 3;
        int j    = r & 7;
        int k    = c * 32 + ((lane >> 4) << 3) + j;
        half_t val = (half_t)0.f;
        if (k < 72) {
            int t = k >> 2, l = k & 3;
            int g = (t >= 9) ? 1 : 0;
            int tap = t - 9 * g;
            int oc  = lane & 15;
            val = (half_t)w2g[(oc * 8 + g * 4 + l) * 9 + tap];
        }
        w2B[i] = val;
    }
    // stage-3 B-fragments: GEMM M=16(img*4+win), N=16/tile (oc=tile*16+n), K=144 (k=tap*16+ic)
    for (int i = tid; i < 5120; i += 256) {
        int j    = i & 7;
        int lane = (i >> 3) & 63;
        int tc   = i >> 9;            // 0..9
        int tile = tc / 5;
        int c    = tc - tile * 5;
        int k    = c * 32 + ((lane >> 4) << 3) + j;
        int n    = lane & 15;
        half_t val = (half_t)0.f;
        if (k < 144) {
            int ic = k & 15, tap = k >> 4;
            val = (half_t)w3g[((tile * 16 + n) * 16 + ic) * 9 + tap];
        }
        w3B[i] = val;
    }
}

// 4 images per block (grid 2048), 256 threads; wave = image for stage 2.
// fp16 image in LDS (~15.9 KB); launch_bounds(256,6): VGPR headroom > occupancy rounds
// (R11/R17 both showed VGPR caps below the working set regress more than the tail costs).
__global__ __launch_bounds__(256, 6) void cnn_kernel(
    const float* __restrict__ seq,
    const float* __restrict__ w1g, const float* __restrict__ b1g,
    const float* __restrict__ b2g, const float* __restrict__ b3g,
    const float* __restrict__ bdg, const float* __restrict__ wsW,
    float* __restrict__ out)
{
    __shared__ __align__(16) half_t s_img2[4][28][28];      // parity: [0..13]=even, [14..27]=odd
    __shared__ __align__(16) half_t s_p1n[4][2][10][11][4]; // [img][g][y][slot][l]; ic=g*4+l
    __shared__ __align__(16) half_t s_p2n[4][16][16];       // [img][pixel(y*4+x)][16 ic]
    __shared__ float s_p3[4][32];

    const int tid   = threadIdx.x;
    const int mbase = blockIdx.x * 4;
    const float*  wdt = wsW;
    const half_t* w2B = (const half_t*)(wsW + 320);
    const half_t* w3B = (const half_t*)(wsW + 1088);

    // ---- stage images (parity de-interleave, fp32 -> fp16)
    if (tid < 196) {
        #pragma unroll
        for (int img = 0; img < 4; img++) {
            const int m = mbase + img;
            const int b = m & 255, nn = m >> 8;
            const int t = nn >> 2, dd = nn & 3;
            const float4* s4 = (const float4*)(seq + (((size_t)b * 8 + t) * 4 + dd) * 784);
            float4 v = s4[tid];
            int flat = tid * 4;
            int r  = flat / 28;
            int cb = flat - r * 28;       // multiple of 4
            int e  = cb >> 1;             // even
            h2 ev = { (half_t)v.x, (half_t)v.z };
            h2 od = { (half_t)v.y, (half_t)v.w };
            *(h2*)&s_img2[img][r][e]      = ev;
            *(h2*)&s_img2[img][r][14 + e] = od;
        }
    }
    __syncthreads();

    // ---- stage 1: conv1(1->8)+relu+pool2 at the 100 needed positions/image (400 items).
    for (int idx = tid; idx < 400; idx += 256) {
        const int img = idx / 100;
        const int rem = idx - img * 100;
        const int y   = rem / 10;
        const int x   = rem - y * 10;
        const int r0  = 2 * y;
        float p[4][4];
        #pragma unroll
        for (int i = 0; i < 4; i++) {
            const half_t* rp = &s_img2[img][r0 + i][0];
            h2 e2 = *(const h2*)&rp[x];        // cols 2x, 2x+2
            h2 o2 = *(const h2*)&rp[14 + x];   // cols 2x+1, 2x+3
            p[i][0] = (float)e2[0];
            p[i][1] = (float)o2[0];
            p[i][2] = (float)e2[1];
            p[i][3] = (float)o2[1];
        }
        float res[8];
        #pragma unroll
        for (int c = 0; c < 8; c++) {
            float w[9];
            #pragma unroll
            for (int k = 0; k < 9; k++) w[k] = w1g[c * 9 + k];   // uniform -> s_load
            const float bias = b1g[c];
            float acc = 0.f;
            #pragma unroll
            for (int rr = 0; rr < 2; rr++)
                #pragma unroll
                for (int cc = 0; cc < 2; cc++) {
                    float v = bias;
                    #pragma unroll
                    for (int i = 0; i < 3; i++)
                        #pragma unroll
                        for (int j = 0; j < 3; j++)
                            v += p[rr + i][cc + j] * w[i * 3 + j];
                    acc += fmaxf(v, 0.f);
                }
            res[c] = 0.25f * acc;
        }
        const int slot = (x >> 1) + 5 * (x & 1);
        h4 lo = { (half_t)res[0], (half_t)res[1], (half_t)res[2], (half_t)res[3] };
        h4 hi = { (half_t)res[4], (half_t)res[5], (half_t)res[6], (half_t)res[7] };
        *(h4*)&s_p1n[img][0][y][slot][0] = lo;
        *(h4*)&s_p1n[img][1][y][slot][0] = hi;
    }
    __syncthreads();

    const int img2 = tid >> 6;          // wave = image (stage 2)
    const int t6   = tid & 63;

    // ---- stage 2 (MFMA): conv2 at 8x8 conv grid + relu + pool -> s_p2n.
    {
        const int q  = t6 >> 4;
        const int oc = t6 & 15;
        int tg[6], ti[6], tj[6];
        bool tv[6];
        #pragma unroll
        for (int c = 0; c < 3; c++)
            #pragma unroll
            for (int s = 0; s < 2; s++) {
                int e = c * 2 + s;
                int t = c * 8 + q * 2 + s;
                bool v = (t < 18);
                int tt = v ? t : 0;
                int g = (tt >= 9) ? 1 : 0;
                int tap = tt - 9 * g;
                tg[e] = g; ti[e] = tap / 3; tj[e] = tap - 3 * (tap / 3); tv[e] = v;
            }
        f16x8 B[3];
        #pragma unroll
        for (int c = 0; c < 3; c++)
            B[c] = *(const f16x8*)&w2B[(c * 64 + t6) * 8];

        const float bias = b2g[oc];
        f32x4 acc[4];
        #pragma unroll
        for (int T = 0; T < 4; T++) {
            acc[T][0] = bias; acc[T][1] = bias; acc[T][2] = bias; acc[T][3] = bias;
        }
        const int mm = t6 & 15;
        #pragma unroll
        for (int T = 0; T < 4; T++) {
            const int cy = 2 * T + (mm >> 3);
            const int cx = mm & 7;
            #pragma unroll
            for (int c = 0; c < 3; c++) {
                h4 a0, a1;
                #pragma unroll
                for (int z = 0; z < 4; z++) { a0[z] = (half_t)0.f; a1[z] = (half_t)0.f; }
                const int e0 = c * 2, e1 = c * 2 + 1;
                if (tv[e0]) {
                    int col = cx + tj[e0];
                    int slot = (col >> 1) + 5 * (col & 1);
                    a0 = *(const h4*)&s_p1n[img2][tg[e0]][cy + ti[e0]][slot][0];
                }
                if (tv[e1]) {
                    int col = cx + tj[e1];
                    int slot = (col >> 1) + 5 * (col & 1);
                    a1 = *(const h4*)&s_p1n[img2][tg[e1]][cy + ti[e1]][slot][0];
                }
                f16x8 A = __builtin_shufflevector(a0, a1, 0, 1, 2, 3, 4, 5, 6, 7);
                acc[T] = __builtin_amdgcn_mfma_f32_16x16x32_f16(A, B[c], acc[T], 0, 0, 0);
            }
        }
        #pragma unroll
        for (int T = 0; T < 4; T++) {
            float p0 = fmaxf(acc[T][0], 0.f) + fmaxf(acc[T][1], 0.f);
            float p1 = fmaxf(acc[T][2], 0.f) + fmaxf(acc[T][3], 0.f);
            p0 += __shfl_xor(p0, 32, 64);          // pool over cy
            p1 += __shfl_xor(p1, 32, 64);
            if (q < 2) {
                s_p2n[img2][T * 4 + q * 2    ][oc] = (half_t)(0.25f * p0);
                s_p2n[img2][T * 4 + q * 2 + 1][oc] = (half_t)(0.25f * p1);
            }
        }
    }
    __syncthreads();

    // ---- stage 3 (MFMA, block-level): waves 0/1; tile = wave (oc base tile*16).
    if ((tid >> 6) < 2) {
        const int tile = tid >> 6;
        const int lane = tid & 63;
        const int n    = lane & 15;
        const int quad = lane >> 4;
        const int oc   = tile * 16 + n;
        const int am   = lane & 15;            // A row index held by this lane
        const int aimg = am >> 2;
        const int awin = am & 3;
        const int au   = awin >> 1, av = awin & 1;
        const int icb  = (quad & 1) * 8;

        float bias = b3g[oc];
        f32x4 acc;
        acc[0] = bias; acc[1] = bias; acc[2] = bias; acc[3] = bias;
        #pragma unroll
        for (int c = 0; c < 5; c++) {
            const int tap = c * 2 + (quad >> 1);
            f16x8 A;
            if (tap < 9) {
                const int i = tap / 3, j = tap - 3 * i;
                A = *(const f16x8*)&s_p2n[aimg][(au + i) * 4 + (av + j)][icb];
            } else {
                #pragma unroll
                for (int z = 0; z < 8; z++) A[z] = (half_t)0.f;
            }
            f16x8 B = *(const f16x8*)&w3B[((tile * 5 + c) * 64 + lane) * 8];
            acc = __builtin_amdgcn_mfma_f32_16x16x32_f16(A, B, acc, 0, 0, 0);
        }
        float s = fmaxf(acc[0], 0.f) + fmaxf(acc[1], 0.f) +
                  fmaxf(acc[2], 0.f) + fmaxf(acc[3], 0.f);
        s_p3[quad][oc] = 0.25f * s;
    }
    __syncthreads();

    // ---- dense + shfl softmax + guards (per wave = per image)
    {
        float logit = -1e30f;
        if (t6 < 10) {
            float acc = bdg[t6];
            #pragma unroll
            for (int c2 = 0; c2 < 32; c2++) acc += s_p3[img2][c2] * wdt[c2 * 10 + t6];
            logit = acc;
        }
        float mx = logit;
        #pragma unroll
        for (int s = 1; s < 16; s <<= 1) mx = fmaxf(mx, __shfl_xor(mx, s, 16));
        float e = (t6 < 10) ? __expf(logit - mx) : 0.f;
        float ssum = e;
        #pragma unroll
        for (int s = 1; s < 16; s <<= 1) ssum += __shfl_xor(ssum, s, 16);
        float p = e / ssum;                        // lanes 10..15 -> p = 0
        const int m = mbase + img2;
        if (t6 < 10) out[(size_t)m * 10 + t6] = p; // all_cnn_preds (N,B,10)

        // guards: [p8, p4+p6, p0+p2, p7+p9, p5, p1+p3]; 0xF slot reads lane 15 (p=0)
        const int sh = (t6 < 6 ? t6 : 0) * 4;
        const int ia = (0x157048 >> sh) & 0xF;
        const int ib = (0x3F926F >> sh) & 0xF;
        float pa = __shfl(p, ia, 16);
        float pb = __shfl(p, ib, 16);
        if (t6 < 6)
            out[81920 + (size_t)m * 6 + t6] = pa + pb;    // all_guard_preds (N,B,6)
    }
}

// 11 blocks x 256 threads. lane = bb*10 + j inside a wave (6 batches/wave).
__global__ __launch_bounds__(256) void sfa_kernel(
    const float* __restrict__ trans,
    const float* __restrict__ out_guards,   // = out (guards at +81920)
    float* __restrict__ out)
{
    __shared__ float M[600];           // [r][i][j]
    const int tid  = threadIdx.x;
    const int lane = tid & 63;
    const int wv   = tid >> 6;

    if (tid < 54) {
        int r = tid / 9, i = tid - r * 9;
        const float* row = trans + (size_t)(r * 9 + i) * 10;
        float x[10], mx = -1e30f;
        #pragma unroll
        for (int j = 0; j < 10; j++) { x[j] = 10.f * row[j]; mx = fmaxf(mx, x[j]); }
        float s = 0.f;
        #pragma unroll
        for (int j = 0; j < 10; j++) { x[j] = __expf(x[j] - mx); s += x[j]; }
        float inv = 1.f / s;
        #pragma unroll
        for (int j = 0; j < 10; j++) M[(r * 9 + i) * 10 + j] = x[j] * inv;
    }
    __syncthreads();

    const int bb    = lane / 10;
    const int j     = lane - bb * 10;
    const int base  = bb * 10;
    const bool ok   = (bb < 6);
    int batch = blockIdx.x * 24 + wv * 6 + bb;
    const bool live = ok && (batch < 256);
    if (!live) batch = 0;

    float Mreg[54];
    #pragma unroll
    for (int k = 0; k < 54; k++) Mreg[k] = M[k * 10 + j];

    float stj = (j == 0) ? 1.f : 0.f;
    const float* gbase = out_guards + 81920;

    for (int nn = 0; nn < 32; nn++) {
        const float* gp = gbase + ((size_t)nn * 256 + batch) * 6;
        float2 ga = *(const float2*)(gp);
        float2 gb = *(const float2*)(gp + 2);
        float2 gc = *(const float2*)(gp + 4);
        float g[6] = {ga.x, ga.y, gb.x, gb.y, gc.x, gc.y};

        float st[10];
        #pragma unroll
        for (int i = 0; i < 10; i++) st[i] = __shfl(stj, base + i, 64);

        float gsum = g[0] + g[1] + g[2] + g[3] + g[4] + g[5];
        float ns = (j == 9) ? gsum * st[9] : 0.f;   // accepting row
        #pragma unroll
        for (int r = 0; r < 6; r++) {
            float h = 0.f;
            #pragma unroll
            for (int i = 0; i < 9; i++) h += st[i] * Mreg[r * 9 + i];
            ns += g[r] * h;
        }
        stj = ns;
    }
    if (live) out[131072 + (size_t)batch * 10 + j] = stj;   // state_final (B,10)
}

extern "C" void kernel_launch(void* const* d_in, const int* in_sizes, int n_in,
                              void* d_out, int out_size, void* d_ws, size_t ws_size,
                              hipStream_t stream) {
    const float* seq = (const float*)d_in[0];
    const float* w1  = (const float*)d_in[1];
    const float* b1  = (const float*)d_in[2];
    const float* w2  = (const float*)d_in[3];
    const float* b2  = (const float*)d_in[4];
    const float* w3  = (const float*)d_in[5];
    const float* b3  = (const float*)d_in[6];
    const float* wd  = (const float*)d_in[7];
    const float* bd  = (const float*)d_in[8];
    const float* tr  = (const float*)d_in[9];
    float* out = (float*)d_out;
    float* wsW = (float*)d_ws;             // wdt + w2B + w3B fragments

    prep_kernel<<<1, 256, 0, stream>>>(w2, w3, wd, wsW);
    cnn_kernel<<<2048, 256, 0, stream>>>(seq, w1, b1, b2, b3, bd, wsW, out);
    sfa_kernel<<<11, 256, 0, stream>>>(tr, out, out);
}